// Round 8
// baseline (155.296 us; speedup 1.0000x reference)
//
#include <hip/hip_runtime.h>

// ---------- complex helpers ----------
__device__ __forceinline__ float2 cmul(float2 a, float2 b) {
    return make_float2(a.x*b.x - a.y*b.y, a.x*b.y + a.y*b.x);
}
__device__ __forceinline__ float2 cfma(float2 a, float2 b, float2 acc) {
    acc.x = fmaf(a.x, b.x, fmaf(-a.y, b.y, acc.x));
    acc.y = fmaf(a.x, b.y, fmaf( a.y, b.x, acc.y));
    return acc;
}
// acc += conj(a) * b
__device__ __forceinline__ float2 cfma_conj(float2 a, float2 b, float2 acc) {
    acc.x = fmaf(a.x, b.x, fmaf( a.y, b.y, acc.x));
    acc.y = fmaf(a.x, b.y, fmaf(-a.y, b.x, acc.y));
    return acc;
}

__device__ __forceinline__ float fast_tanh(float x) {
    const float e = __expf(2.0f * x);
    return 1.0f - 2.0f / (e + 1.0f);
}

// ---------- single fused kernel ----------
// Per block of 256 threads (covering 256 batch rows):
//  (1) issue cooperative loads of the FIRST 64 B of each row (4 lanes/row,
//      16 fully-used 64B lines per wave instr; FETCH = HW minimum 33.5 MB).
//  (2) wave 0 (t<16) builds Mq columns, wave 1 (t in [64,80)) builds Mk
//      columns — two parallel serial chains on different SIMDs, ~2-3 us,
//      hidden under the in-flight global loads.
//  (3) barrier; t<16 form G = Mq^dagger Mk into LDS; loaders stage rows.
//  (4) barrier; all 256 threads do the bilinear form, coalesced out-write.
__global__ __launch_bounds__(256)
void qdp_fused(const float* __restrict__ Q, const float* __restrict__ K,
               const float* __restrict__ Wq, const float* __restrict__ Wk,
               float* __restrict__ out) {
    __shared__ float2 Gs[256];
    __shared__ float2 MqL[16][16];                  // [row][col]
    __shared__ float2 MkL[16][16];
    __shared__ float4 lq[256], lk[256];

    const int t = threadIdx.x;
    const long b0 = (long)blockIdx.x * 256;
    const float4* Qb = reinterpret_cast<const float4*>(Q + b0 * 64);
    const float4* Kb = reinterpret_cast<const float4*>(K + b0 * 64);

    // (1) cooperative loads first — nothing delays vmem issue.
    // f = s*256 + t ; row = f>>2 ; j = f&3 ; float4 idx = row*16 + j.
    float4 vq[4], vk[4];
    #pragma unroll
    for (int s = 0; s < 4; ++s) {
        const int f   = s * 256 + t;
        const int idx = ((f >> 2) << 4) + (f & 3);
        vq[s] = Qb[idx];
        vk[s] = Kb[idx];
    }

    // (2) circuit build: wave 0 -> Mq, wave 1 -> Mk (parallel SIMDs).
    const bool isQ = (t < 16);
    const bool isK = (t >= 64 && t < 80);
    if (isQ || isK) {
        const int col  = isK ? (t - 64) : t;
        const float* W = isK ? Wk : Wq;
        float2 c[16];
        #pragma unroll
        for (int x = 0; x < 16; ++x)
            c[x] = make_float2(x == col ? 1.0f : 0.0f, 0.0f);

        #pragma unroll
        for (int layer = 0; layer < 2; ++layer) {
            #pragma unroll
            for (int w = 0; w < 4; ++w) {
                const int mask = 1 << (3 - w);      // wire w <-> bit (3-w)
                const float* wp = W + layer*12 + w*3;
                const float phi = wp[0], th = wp[1], om = wp[2];
                const float ht = 0.5f*th, ap = 0.5f*(phi+om), am = 0.5f*(phi-om);
                const float cc  = __cosf(ht),  ss  = __sinf(ht);
                const float cap = __cosf(ap),  sap = __sinf(ap);
                const float cam = __cosf(am),  sam = __sinf(am);
                const float2 u00 = make_float2( cc*cap, -cc*sap);
                const float2 u01 = make_float2(-ss*cam, -ss*sam);
                const float2 u10 = make_float2( ss*cam, -ss*sam);
                const float2 u11 = make_float2( cc*cap,  cc*sap);
                #pragma unroll
                for (int x = 0; x < 16; ++x) {
                    if (x & mask) continue;
                    const int y = x | mask;
                    const float2 a = c[x], b = c[y];
                    float2 nx = cmul(u00, a); nx = cfma(u01, b, nx);
                    float2 ny = cmul(u10, a); ny = cfma(u11, b, ny);
                    c[x] = nx; c[y] = ny;
                }
            }
            #pragma unroll
            for (int w = 0; w < 3; ++w) {           // CNOT(w, w+1)
                const int mc = 1 << (3 - w);
                const int mt = 1 << (2 - w);
                #pragma unroll
                for (int x = 0; x < 16; ++x) {
                    if ((x & mc) && !(x & mt)) {
                        const int y = x | mt;
                        const float2 tmp = c[x]; c[x] = c[y]; c[y] = tmp;
                    }
                }
            }
        }
        #pragma unroll
        for (int kx = 0; kx < 16; ++kx) {
            if (isK) MkL[kx][col] = c[kx];
            else     MqL[kx][col] = c[kx];
        }
    }
    __syncthreads();

    // (3a) G[i][t] = sum_k conj(Mq[k][i]) * Mk[k][t]   (threads 0..15)
    if (t < 16) {
        #pragma unroll
        for (int i = 0; i < 16; ++i) {
            float2 acc = make_float2(0.0f, 0.0f);
            #pragma unroll
            for (int kx = 0; kx < 16; ++kx)
                acc = cfma_conj(MqL[kx][i], MkL[kx][t], acc);
            Gs[i*16 + t] = acc;
        }
    }
    // (3b) stage needed float4 (j==0 of each row) to LDS.
    if ((t & 3) == 0) {
        #pragma unroll
        for (int s = 0; s < 4; ++s) {
            const int row = s * 64 + (t >> 2);
            lq[row] = vq[s];
            lk[row] = vk[s];
        }
    }
    __syncthreads();

    // (4) bilinear form for row t of this block.
    const float4 qv = lq[t];
    const float4 kv = lk[t];

    float cqa[4], sqa[4], cka[4], ska[4];
    {
        const float qa[4] = {qv.x, qv.y, qv.z, qv.w};
        const float ka[4] = {kv.x, kv.y, kv.z, kv.w};
        #pragma unroll
        for (int i = 0; i < 4; ++i) {
            const float tq = fast_tanh(qa[i]) * 1.57079632679489662f;
            const float tk = fast_tanh(ka[i]) * 1.57079632679489662f;
            __sincosf(tq, &sqa[i], &cqa[i]);
            __sincosf(tk, &ska[i], &cka[i]);
        }
    }

    // product-state amplitudes; idx bits (b3 b2 b1 b0) <-> qubits (0 1 2 3)
    const float pq01[4] = {cqa[0]*cqa[1], cqa[0]*sqa[1], sqa[0]*cqa[1], sqa[0]*sqa[1]};
    const float pq23[4] = {cqa[2]*cqa[3], cqa[2]*sqa[3], sqa[2]*cqa[3], sqa[2]*sqa[3]};
    const float pk01[4] = {cka[0]*cka[1], cka[0]*ska[1], ska[0]*cka[1], ska[0]*ska[1]};
    const float pk23[4] = {cka[2]*cka[3], cka[2]*ska[3], ska[2]*cka[3], ska[2]*ska[3]};

    float bk[16];
    #pragma unroll
    for (int j = 0; j < 16; ++j) bk[j] = pk01[j >> 2] * pk23[j & 3];

    float ovr = 0.0f, ovi = 0.0f;
    #pragma unroll
    for (int i = 0; i < 16; ++i) {
        float wr = 0.0f, wi = 0.0f;
        #pragma unroll
        for (int j = 0; j < 16; ++j) {
            const float2 g = Gs[i*16 + j];          // wave-uniform -> broadcast
            wr = fmaf(g.x, bk[j], wr);
            wi = fmaf(g.y, bk[j], wi);
        }
        const float ai = pq01[i >> 2] * pq23[i & 3];
        ovr = fmaf(ai, wr, ovr);
        ovi = fmaf(ai, wi, ovi);
    }

    out[b0 + t] = fmaf(0.5f, ovr*ovr + ovi*ovi, 0.5f);
}

extern "C" void kernel_launch(void* const* d_in, const int* in_sizes, int n_in,
                              void* d_out, int out_size, void* d_ws, size_t ws_size,
                              hipStream_t stream) {
    const float* query = (const float*)d_in[0];
    const float* key   = (const float*)d_in[1];
    const float* Wq    = (const float*)d_in[2];
    const float* Wk    = (const float*)d_in[3];
    float* out = (float*)d_out;

    const int B = in_sizes[0] / 64;                 // 262144; B % 256 == 0

    qdp_fused<<<B / 256, 256, 0, stream>>>(query, key, Wq, Wk, out);
}

// Round 9
// 138.688 us; speedup vs baseline: 1.1198x; 1.1198x over previous
//
#include <hip/hip_runtime.h>

// ---------- complex helpers ----------
__device__ __forceinline__ float2 cmul(float2 a, float2 b) {
    return make_float2(a.x*b.x - a.y*b.y, a.x*b.y + a.y*b.x);
}
__device__ __forceinline__ float2 cfma(float2 a, float2 b, float2 acc) {
    acc.x = fmaf(a.x, b.x, fmaf(-a.y, b.y, acc.x));
    acc.y = fmaf(a.x, b.y, fmaf( a.y, b.x, acc.y));
    return acc;
}
// acc += conj(a) * b
__device__ __forceinline__ float2 cfma_conj(float2 a, float2 b, float2 acc) {
    acc.x = fmaf(a.x, b.x, fmaf( a.y, b.y, acc.x));
    acc.y = fmaf(a.x, b.y, fmaf(-a.y, b.x, acc.y));
    return acc;
}

__device__ __forceinline__ float fast_tanh(float x) {
    const float e = __expf(2.0f * x);
    return 1.0f - 2.0f / (e + 1.0f);
}

// ---------- single fused kernel, wave-specialized ----------
// Waves 2/3 (t>=128): cooperative fetch of first 64 B of each of the block's
//   256 rows (consecutive lanes -> consecutive 16 B, every 64 B line fully
//   used), staged STRAIGHT to LDS — no registers live across phases (round-8
//   counters showed 30 MB of scratch spill writes from cross-phase liveness).
// Waves 0/1: t<16 builds Mq columns, 64<=t<80 builds Mk columns (parallel
//   serial chains on different SIMDs), overlapping the loaders' HBM latency.
// Then: all 256 threads form G = Mq^dagger Mk (one entry each), barrier,
//   bilinear form, coalesced out-write.
__global__ __launch_bounds__(256)
void qdp_fused(const float* __restrict__ Q, const float* __restrict__ K,
               const float* __restrict__ Wq, const float* __restrict__ Wk,
               float* __restrict__ out) {
    __shared__ float2 Gs[256];
    __shared__ float2 MqL[16][16];                  // [row][col]
    __shared__ float2 MkL[16][16];
    __shared__ float4 lq[256], lk[256];

    const int t = threadIdx.x;
    const long b0 = (long)blockIdx.x * 256;
    const float4* Qb = reinterpret_cast<const float4*>(Q + b0 * 64);
    const float4* Kb = reinterpret_cast<const float4*>(K + b0 * 64);

    if (t >= 128) {
        // ---- loader waves ----
        const int lt = t - 128;                     // 0..127
        float4 vq[8], vk[8];
        #pragma unroll
        for (int s = 0; s < 8; ++s) {
            const int f   = s * 128 + lt;           // 0..1023
            const int idx = ((f >> 2) << 4) + (f & 3);  // row*16 + j
            vq[s] = Qb[idx];
            vk[s] = Kb[idx];
        }
        #pragma unroll
        for (int s = 0; s < 8; ++s) {
            const int f = s * 128 + lt;
            if ((f & 3) == 0) {                     // keep j==0 of each row
                lq[f >> 2] = vq[s];
                lk[f >> 2] = vk[s];
            }
        }
    } else {
        // ---- builder waves ----
        const bool isQ = (t < 16);
        const bool isK = (t >= 64 && t < 80);
        if (isQ || isK) {
            const int col  = isK ? (t - 64) : t;
            const float* W = isK ? Wk : Wq;
            float2 c[16];
            #pragma unroll
            for (int x = 0; x < 16; ++x)
                c[x] = make_float2(x == col ? 1.0f : 0.0f, 0.0f);

            #pragma unroll
            for (int layer = 0; layer < 2; ++layer) {
                #pragma unroll
                for (int w = 0; w < 4; ++w) {
                    const int mask = 1 << (3 - w);  // wire w <-> bit (3-w)
                    const float* wp = W + layer*12 + w*3;
                    const float phi = wp[0], th = wp[1], om = wp[2];
                    const float ht = 0.5f*th, ap = 0.5f*(phi+om), am = 0.5f*(phi-om);
                    const float cc  = __cosf(ht),  ss  = __sinf(ht);
                    const float cap = __cosf(ap),  sap = __sinf(ap);
                    const float cam = __cosf(am),  sam = __sinf(am);
                    const float2 u00 = make_float2( cc*cap, -cc*sap);
                    const float2 u01 = make_float2(-ss*cam, -ss*sam);
                    const float2 u10 = make_float2( ss*cam, -ss*sam);
                    const float2 u11 = make_float2( cc*cap,  cc*sap);
                    #pragma unroll
                    for (int x = 0; x < 16; ++x) {
                        if (x & mask) continue;
                        const int y = x | mask;
                        const float2 a = c[x], b = c[y];
                        float2 nx = cmul(u00, a); nx = cfma(u01, b, nx);
                        float2 ny = cmul(u10, a); ny = cfma(u11, b, ny);
                        c[x] = nx; c[y] = ny;
                    }
                }
                #pragma unroll
                for (int w = 0; w < 3; ++w) {       // CNOT(w, w+1)
                    const int mc = 1 << (3 - w);
                    const int mt = 1 << (2 - w);
                    #pragma unroll
                    for (int x = 0; x < 16; ++x) {
                        if ((x & mc) && !(x & mt)) {
                            const int y = x | mt;
                            const float2 tmp = c[x]; c[x] = c[y]; c[y] = tmp;
                        }
                    }
                }
            }
            #pragma unroll
            for (int kx = 0; kx < 16; ++kx) {
                if (isK) MkL[kx][col] = c[kx];
                else     MqL[kx][col] = c[kx];
            }
        }
    }
    __syncthreads();

    // G entry per thread: Gs[i*16+j] = sum_k conj(Mq[k][i]) * Mk[k][j]
    {
        const int i = t >> 4, j = t & 15;
        float2 acc = make_float2(0.0f, 0.0f);
        #pragma unroll
        for (int kx = 0; kx < 16; ++kx)
            acc = cfma_conj(MqL[kx][i], MkL[kx][j], acc);
        Gs[t] = acc;
    }
    __syncthreads();

    // bilinear form for row t of this block.
    const float4 qv = lq[t];
    const float4 kv = lk[t];

    float cqa[4], sqa[4], cka[4], ska[4];
    {
        const float qa[4] = {qv.x, qv.y, qv.z, qv.w};
        const float ka[4] = {kv.x, kv.y, kv.z, kv.w};
        #pragma unroll
        for (int i = 0; i < 4; ++i) {
            const float tq = fast_tanh(qa[i]) * 1.57079632679489662f;
            const float tk = fast_tanh(ka[i]) * 1.57079632679489662f;
            __sincosf(tq, &sqa[i], &cqa[i]);
            __sincosf(tk, &ska[i], &cka[i]);
        }
    }

    // product-state amplitudes; idx bits (b3 b2 b1 b0) <-> qubits (0 1 2 3)
    const float pq01[4] = {cqa[0]*cqa[1], cqa[0]*sqa[1], sqa[0]*cqa[1], sqa[0]*sqa[1]};
    const float pq23[4] = {cqa[2]*cqa[3], cqa[2]*sqa[3], sqa[2]*cqa[3], sqa[2]*sqa[3]};
    const float pk01[4] = {cka[0]*cka[1], cka[0]*ska[1], ska[0]*cka[1], ska[0]*ska[1]};
    const float pk23[4] = {cka[2]*cka[3], cka[2]*ska[3], ska[2]*cka[3], ska[2]*ska[3]};

    float bk[16];
    #pragma unroll
    for (int j = 0; j < 16; ++j) bk[j] = pk01[j >> 2] * pk23[j & 3];

    float ovr = 0.0f, ovi = 0.0f;
    #pragma unroll
    for (int i = 0; i < 16; ++i) {
        float wr = 0.0f, wi = 0.0f;
        #pragma unroll
        for (int j = 0; j < 16; ++j) {
            const float2 g = Gs[i*16 + j];          // wave-uniform -> broadcast
            wr = fmaf(g.x, bk[j], wr);
            wi = fmaf(g.y, bk[j], wi);
        }
        const float ai = pq01[i >> 2] * pq23[i & 3];
        ovr = fmaf(ai, wr, ovr);
        ovi = fmaf(ai, wi, ovi);
    }

    out[b0 + t] = fmaf(0.5f, ovr*ovr + ovi*ovi, 0.5f);
}

extern "C" void kernel_launch(void* const* d_in, const int* in_sizes, int n_in,
                              void* d_out, int out_size, void* d_ws, size_t ws_size,
                              hipStream_t stream) {
    const float* query = (const float*)d_in[0];
    const float* key   = (const float*)d_in[1];
    const float* Wq    = (const float*)d_in[2];
    const float* Wk    = (const float*)d_in[3];
    float* out = (float*)d_out;

    const int B = in_sizes[0] / 64;                 // 262144; B % 256 == 0

    qdp_fused<<<B / 256, 256, 0, stream>>>(query, key, Wq, Wk, out);
}